// Round 14
// baseline (1668.872 us; speedup 1.0000x reference)
//
#include <hip/hip_runtime.h>
#include <math.h>

#define B 128
#define T 128
#define H 256
#define E 300
#define HD4 1024
#define D2H 512

typedef unsigned short u16;
typedef unsigned char u8;
typedef unsigned int u32;
typedef unsigned long long u64;
typedef __attribute__((ext_vector_type(8))) short bf16x8;
typedef __attribute__((ext_vector_type(4))) float f32x4;
typedef __attribute__((ext_vector_type(2))) float f32x2;
typedef __attribute__((address_space(1))) void as1_void;
typedef __attribute__((address_space(3))) void as3_void;

__device__ __forceinline__ float sigm(float x) { return 1.0f / (1.0f + expf(-x)); }
__device__ __forceinline__ float fast_sigm(float x) { return 1.0f / (1.0f + __expf(-x)); }
__device__ __forceinline__ float fast_tanh(float x) {
    return 1.0f - 2.0f / (__expf(2.0f * x) + 1.0f);
}
__device__ __forceinline__ float b2f(u16 u) { return __uint_as_float(((u32)u) << 16); }
__device__ __forceinline__ u16 f2b(float f) {
    u32 u = __float_as_uint(f);
    u32 r = u + 0x7FFFu + ((u >> 16) & 1u);
    return (u16)(r >> 16);
}

// ---------- embedding gather + cast + pad to K=320 ----------
__global__ __launch_bounds__(256) void k_cast_emb(const int* __restrict__ ids,
                                                  const float* __restrict__ tab,
                                                  u16* __restrict__ dst) {
    int idx = blockIdx.x * 256 + threadIdx.x;
    int row = idx / 40, kc = (idx - row * 40) * 8;
    if (row >= B * T) return;
    int id = ids[row];
    const float* src = tab + (size_t)id * E + kc;
    bf16x8 v;
#pragma unroll
    for (int j = 0; j < 8; ++j) {
        float fv = 0.0f;
        if (kc + j < E) fv = src[j];
        v[j] = (short)f2b(fv);
    }
    *(bf16x8*)(dst + (size_t)row * 320 + kc) = v;
}

// ---------- generic fp32 [N][Kin] -> bf16 [N][Kpad] ----------
__global__ __launch_bounds__(256) void k_cast_pad(const float* __restrict__ src,
                                                  u16* __restrict__ dst,
                                                  int N, int Kin, int Kpad) {
    int idx = blockIdx.x * 256 + threadIdx.x;
    int rk = Kpad >> 3;
    int row = idx / rk, kc = (idx - row * rk) * 8;
    if (row >= N) return;
    const float* s = src + (size_t)row * Kin + kc;
    bf16x8 v;
#pragma unroll
    for (int j = 0; j < 8; ++j) {
        float fv = 0.0f;
        if (kc + j < Kin) fv = s[j];
        v[j] = (short)f2b(fv);
    }
    *(bf16x8*)(dst + (size_t)row * Kpad + kc) = v;
}

// ---------- Whh f32 [1024][256] -> fp8 (x16 scale) ----------
__global__ __launch_bounds__(256) void k_cast_w8(const float* __restrict__ src,
                                                 u8* __restrict__ dst) {
    int idx = blockIdx.x * 256 + threadIdx.x;
    if (idx >= 65536) return;
    const float* s = src + (size_t)idx * 4;
    u32 r = __builtin_amdgcn_cvt_pk_fp8_f32(s[0] * 16.0f, s[1] * 16.0f, 0, false);
    r = __builtin_amdgcn_cvt_pk_fp8_f32(s[2] * 16.0f, s[3] * 16.0f, r, true);
    *(u32*)&dst[(size_t)idx * 4] = r;
}

// ---------- MFMA GEMM: xg[(t*B+b)][u*4+g] = bf16( A[m]·W[n] + bias[n] ) ----
__global__ __launch_bounds__(256) void k_gemm_mfma(const u16* __restrict__ A,
                                                   const u16* __restrict__ W,
                                                   const float* __restrict__ bias,
                                                   u16* __restrict__ out, int Kpad) {
    __shared__ u16 aL[128 * 32];
    __shared__ u16 bL[128 * 32];
    const int n0 = blockIdx.x * 128, m0 = blockIdx.y * 128;
    const int tid = threadIdx.x, wid = tid >> 6, l = tid & 63;
    const int wm = wid >> 1, wn = wid & 1;
    const int srow = wid * 16 + (l >> 2);
    const int scol = (l & 3) * 8;

    f32x4 acc[4][4] = {};

    for (int k0 = 0; k0 < Kpad; k0 += 32) {
#pragma unroll
        for (int c = 0; c < 2; ++c) {
            const u16* ga = A + (size_t)(m0 + c * 64 + srow) * Kpad + k0 + scol;
            const u16* gb = W + (size_t)(n0 + c * 64 + srow) * Kpad + k0 + scol;
            __builtin_amdgcn_global_load_lds((const as1_void*)ga,
                                             (as3_void*)&aL[(c * 64 + wid * 16) * 32],
                                             16, 0, 0);
            __builtin_amdgcn_global_load_lds((const as1_void*)gb,
                                             (as3_void*)&bL[(c * 64 + wid * 16) * 32],
                                             16, 0, 0);
        }
        __syncthreads();
        bf16x8 af[4], bf[4];
#pragma unroll
        for (int i = 0; i < 4; ++i)
            af[i] = *(const bf16x8*)&aL[(wm * 64 + i * 16 + (l & 15)) * 32 + (l >> 4) * 8];
#pragma unroll
        for (int j = 0; j < 4; ++j)
            bf[j] = *(const bf16x8*)&bL[(wn * 64 + j * 16 + (l & 15)) * 32 + (l >> 4) * 8];
#pragma unroll
        for (int i = 0; i < 4; ++i)
#pragma unroll
            for (int j = 0; j < 4; ++j)
                acc[i][j] = __builtin_amdgcn_mfma_f32_16x16x32_bf16(af[i], bf[j], acc[i][j], 0, 0, 0);
        __syncthreads();
    }

    float bv[4];
#pragma unroll
    for (int j = 0; j < 4; ++j) bv[j] = bias[n0 + wn * 64 + j * 16 + (l & 15)];
#pragma unroll
    for (int i = 0; i < 4; ++i) {
        int mbase = m0 + wm * 64 + i * 16 + (l >> 4) * 4;
#pragma unroll
        for (int r = 0; r < 4; ++r) {
            int m = mbase + r;
            int bb = m >> 7, tt = m & 127;   // m = b*T + t
            u16* orow = out + (size_t)(tt * B + bb) * HD4;
#pragma unroll
            for (int j = 0; j < 4; ++j) {
                int n = n0 + wn * 64 + j * 16 + (l & 15);
                orow[(n & 255) * 4 + (n >> 8)] = f2b(acc[i][j][r] + bv[j]);
            }
        }
    }
}

// ---------- persistent bi-LSTM recurrence, ZERO cross-block sync, fp8 MFMA ----------
// grid 16 = (d, bc); 512 threads (8 waves). NO persistent weight registers:
// ks 0..3 fp8 in LDS (128KB, resident); ks 4..7 STREAMED from L2 each half-step
// (prefetch issued before the LDS-MFMA block -> latency hidden; 128KB/block/step
// = trivial L2 bandwidth). Peak live regs ~98 < cap -> no scratch spills (R11-R13's
// hidden cost). Raw s_barrier with lgkmcnt(0) only: o-stores & loads are never
// vmcnt-drained at the barrier (no global-mem intra-block communication -> safe).
__global__ __launch_bounds__(512) void k_recur(
    const u16* __restrict__ xg_f, const u16* __restrict__ xg_r,
    const u8* __restrict__ W8f, const u8* __restrict__ W8r,
    const float* __restrict__ h0, const float* __restrict__ c0,
    u16* __restrict__ o) {
    const int bid = blockIdx.x;
    const int d = bid >> 3;
    const int bc = bid & 7;
    const int b0 = bc * 16;
    const u16* xg = d ? xg_r : xg_f;
    const u8* W8 = d ? W8r : W8f;
    const int tid = threadIdx.x, w = tid >> 6, l = tid & 63;
    const int bb = l & 15, q = l >> 4;

    __shared__ u8 wlds[131072];         // fp8 weights, ks 0..3, fragment-linear
    __shared__ u8 h8[2][16][264];       // fp8 h (x16), double-buffered, +8 pad

    // ---- weights ks 0..3 into LDS; precompute stream offsets for ks 4..7
    u32 off[8];
#pragma unroll
    for (int i = 0; i < 8; ++i) {
        int j = 8 * w + i;
        int n = 16 * j + bb;                 // interleaved col n = u*4+g
        int r = (n & 3) * 256 + (n >> 2);    // source row g*256+u
        off[i] = (u32)(r * 256 + 128 + q * 8);   // byte offset of ks=4 fragment
#pragma unroll
        for (int ks = 0; ks < 4; ++ks) {
            u64 v = *(const u64*)&W8[(size_t)r * 256 + ks * 32 + q * 8];
            *(u64*)&wlds[(size_t)((j * 4 + ks) * 512) + l * 8] = v;
        }
    }

    // ---- c-state: 8 cells (bb, u = 32w + 4i + q)
    float creg[8];
#pragma unroll
    for (int i = 0; i < 8; ++i)
        creg[i] = c0[(size_t)(d * B + b0 + bb) * H + 32 * w + 4 * i + q];

    // ---- h(0) -> fp8 x16 (thread owns 8 consecutive bytes)
    {
        int idx = tid * 8;
        int rb = idx >> 8, u0 = idx & 255;
        const float* hp = h0 + (size_t)(d * B + b0 + rb) * H + u0;
        u32 lo = __builtin_amdgcn_cvt_pk_fp8_f32(hp[0] * 16.f, hp[1] * 16.f, 0, false);
        lo = __builtin_amdgcn_cvt_pk_fp8_f32(hp[2] * 16.f, hp[3] * 16.f, lo, true);
        u32 hi = __builtin_amdgcn_cvt_pk_fp8_f32(hp[4] * 16.f, hp[5] * 16.f, 0, false);
        hi = __builtin_amdgcn_cvt_pk_fp8_f32(hp[6] * 16.f, hp[7] * 16.f, hi, true);
        *(u64*)&h8[0][rb][u0] = ((u64)hi << 32) | lo;
    }
    __syncthreads();

    const float S = 1.0f / 256.0f;   // undo x16 (W) * x16 (h)

    for (int s = 0; s < T; ++s) {
        const int t = d ? (T - 1 - s) : s;
        const int p = s & 1;

        // hoist ALL xq loads for the step (xg is L2/L3-resident; ~1200cyc slack)
        u64 xq[8];
#pragma unroll
        for (int i = 0; i < 8; ++i)
            xq[i] = *(const u64*)&xg[((size_t)t * B + b0 + bb) * HD4 +
                                     (32 * w + 4 * i + q) * 4];

#pragma unroll
        for (int hs = 0; hs < 2; ++hs) {
            // stream ks 4..7 weights for this half (issued before LDS-MFMA block)
            u64 ws[4][4];
#pragma unroll
            for (int ii = 0; ii < 4; ++ii)
#pragma unroll
                for (int ks = 0; ks < 4; ++ks)
                    ws[ii][ks] = *(const u64*)&W8[off[4 * hs + ii] + ks * 32];

            f32x4 acc[4] = {};
#pragma unroll
            for (int ks = 0; ks < 4; ++ks) {
                u64 hf = *(const u64*)&h8[p][bb][ks * 32 + q * 8];
#pragma unroll
                for (int ii = 0; ii < 4; ++ii) {
                    int j = 8 * w + 4 * hs + ii;
                    u64 wv = *(const u64*)&wlds[(size_t)((j * 4 + ks) * 512) + l * 8];
                    acc[ii] = __builtin_amdgcn_mfma_f32_16x16x32_fp8_fp8(
                        (long)wv, (long)hf, acc[ii], 0, 0, 0);
                }
            }
#pragma unroll
            for (int ks = 0; ks < 4; ++ks) {
                u64 hf = *(const u64*)&h8[p][bb][(4 + ks) * 32 + q * 8];
#pragma unroll
                for (int ii = 0; ii < 4; ++ii)
                    acc[ii] = __builtin_amdgcn_mfma_f32_16x16x32_fp8_fp8(
                        (long)ws[ii][ks], (long)hf, acc[ii], 0, 0, 0);
            }

            // cell updates
            float hn[4];
#pragma unroll
            for (int ii = 0; ii < 4; ++ii) {
                int i = 4 * hs + ii;
                u64 qv = xq[i];
                float gi_ = acc[ii][0] * S + b2f((u16)qv);
                float gf_ = acc[ii][1] * S + b2f((u16)(qv >> 16));
                float gg_ = acc[ii][2] * S + b2f((u16)(qv >> 32));
                float go_ = acc[ii][3] * S + b2f((u16)(qv >> 48));
                float cn = fast_sigm(gf_) * creg[i] + fast_sigm(gi_) * fast_tanh(gg_);
                hn[ii] = fast_sigm(go_) * fast_tanh(cn);
                creg[i] = cn;
                o[((size_t)(b0 + bb) * T + t) * D2H + d * H + 32 * w + 4 * i + q] = f2b(hn[ii]);
            }
            // h -> fp8 x16, byte writes into next buffer
            u32 pk01 = __builtin_amdgcn_cvt_pk_fp8_f32(hn[0] * 16.f, hn[1] * 16.f, 0, false);
            u32 pk23 = __builtin_amdgcn_cvt_pk_fp8_f32(hn[2] * 16.f, hn[3] * 16.f, 0, false);
            h8[p ^ 1][bb][32 * w + 4 * (4 * hs + 0) + q] = (u8)(pk01 & 0xff);
            h8[p ^ 1][bb][32 * w + 4 * (4 * hs + 1) + q] = (u8)((pk01 >> 8) & 0xff);
            h8[p ^ 1][bb][32 * w + 4 * (4 * hs + 2) + q] = (u8)(pk23 & 0xff);
            h8[p ^ 1][bb][32 * w + 4 * (4 * hs + 3) + q] = (u8)((pk23 >> 8) & 0xff);
        }

        // LDS-only barrier: wait ds ops, do NOT drain vmcnt (o stores/loads float)
        asm volatile("s_waitcnt lgkmcnt(0)" ::: "memory");
        __builtin_amdgcn_s_barrier();
        __builtin_amdgcn_sched_barrier(0);
    }
}

// ---------- gt = sigmoid(o1 · gt_W + gt_b) ----------
__global__ __launch_bounds__(256) void k_gt(const u16* __restrict__ o1,
                                            const float* __restrict__ gtW,
                                            const float* __restrict__ gtb,
                                            float* __restrict__ gt) {
    int row = blockIdx.x * 4 + (threadIdx.x >> 6);
    int lane = threadIdx.x & 63;
    const u16* x = o1 + (size_t)row * D2H;
    float p = 0.f;
    for (int j = lane; j < D2H; j += 64) p += b2f(x[j]) * gtW[j];
#pragma unroll
    for (int off = 32; off; off >>= 1) p += __shfl_down(p, off);
    if (lane == 0) gt[row] = sigm(p + gtb[0]);
}

// ---------- gated temporal scan ----------
__global__ void k_scan(const u16* __restrict__ o2, const float* __restrict__ gt,
                       float* __restrict__ hs2) {
    int b = blockIdx.x >> 1;
    int f = ((blockIdx.x & 1) << 8) + threadIdx.x;
    const u16* src = o2 + (size_t)b * T * D2H + f;
    float* dst = hs2 + (size_t)b * T * D2H + f;
    float prev = b2f(src[0]);
    dst[0] = prev;
    for (int t = 1; t < T; ++t) {
        float g = gt[b * T + t];
        prev = g * b2f(src[(size_t)t * D2H]) + (1.0f - g) * prev;
        dst[(size_t)t * D2H] = prev;
    }
}

// ---------- classifiers + softmax + NLL + argmax ----------
__global__ __launch_bounds__(256) void k_cls(
    const u16* __restrict__ o1, const float* __restrict__ hs2,
    const float* __restrict__ c1W, const float* __restrict__ c1b,
    const float* __restrict__ c2W, const float* __restrict__ c2b,
    const float* __restrict__ c3W, const float* __restrict__ c3b,
    const float* __restrict__ trans, const float* __restrict__ y_op,
    const float* __restrict__ y_bd, const float* __restrict__ y_oe,
    float* __restrict__ out_pred, float* __restrict__ out_loss) {
    int row = blockIdx.x * 4 + (threadIdx.x >> 6);
    int lane = threadIdx.x & 63;
    const u16* x1 = o1 + (size_t)row * D2H;
    const float* x2 = hs2 + (size_t)row * D2H;
    float p1[5] = {}, p2[13] = {}, p3[2] = {};
    for (int j = lane; j < D2H; j += 64) {
        float a = b2f(x1[j]), h = x2[j];
#pragma unroll
        for (int c = 0; c < 5; ++c) p1[c] += a * c1W[c * D2H + j];
#pragma unroll
        for (int c = 0; c < 13; ++c) p2[c] += h * c2W[c * D2H + j];
#pragma unroll
        for (int c = 0; c < 2; ++c) p3[c] += a * c3W[c * D2H + j];
    }
#pragma unroll
    for (int c = 0; c < 5; ++c)
#pragma unroll
        for (int off = 32; off; off >>= 1) p1[c] += __shfl_down(p1[c], off);
#pragma unroll
    for (int c = 0; c < 13; ++c)
#pragma unroll
        for (int off = 32; off; off >>= 1) p2[c] += __shfl_down(p2[c], off);
#pragma unroll
    for (int c = 0; c < 2; ++c)
#pragma unroll
        for (int off = 32; off; off >>= 1) p3[c] += __shfl_down(p3[c], off);

    if (lane == 0) {
        float z1[5], z2[13], z3[2];
        float m = -1e30f, s;
        for (int c = 0; c < 5; ++c) { z1[c] = p1[c] + c1b[c]; m = fmaxf(m, z1[c]); }
        s = 0.f;
        for (int c = 0; c < 5; ++c) { z1[c] = expf(z1[c] - m); s += z1[c]; }
        for (int c = 0; c < 5; ++c) z1[c] /= s;
        m = -1e30f;
        for (int c = 0; c < 13; ++c) { z2[c] = p2[c] + c2b[c]; m = fmaxf(m, z2[c]); }
        s = 0.f;
        for (int c = 0; c < 13; ++c) { z2[c] = expf(z2[c] - m); s += z2[c]; }
        for (int c = 0; c < 13; ++c) z2[c] /= s;
        m = fmaxf(p3[0] + c3b[0], p3[1] + c3b[1]);
        z3[0] = expf(p3[0] + c3b[0] - m);
        z3[1] = expf(p3[1] + c3b[1] - m);
        s = z3[0] + z3[1];
        z3[0] /= s; z3[1] /= s;

        float at = 0.f;
        for (int c = 0; c < 5; ++c) at += z1[c] * z1[c];
        at *= 0.5f;

        float lsum = 0.f, best = -1e30f;
        int arg = 0;
        for (int c = 0; c < 13; ++c) {
            float s2v = 0.f;
            for (int j = 0; j < 5; ++j) s2v += z1[j] * trans[j * 13 + c];
            float v = at * s2v + (1.0f - at) * z2[c];
            lsum += y_op[(size_t)row * 13 + c] * logf(v);
            if (v > best) { best = v; arg = c; }
        }
        for (int j = 0; j < 5; ++j) lsum += y_bd[(size_t)row * 5 + j] * logf(z1[j]);
        for (int k = 0; k < 2; ++k) lsum += y_oe[(size_t)row * 2 + k] * logf(z3[k]);
        atomicAdd(out_loss, -lsum * (1.0f / T));
        out_pred[row] = (float)arg;
    }
}

extern "C" void kernel_launch(void* const* d_in, const int* in_sizes, int n_in,
                              void* d_out, int out_size, void* d_ws, size_t ws_size,
                              hipStream_t stream) {
    const int* ids = (const int*)d_in[0];
    const float* y_op = (const float*)d_in[1];
    const float* y_bd = (const float*)d_in[2];
    const float* y_oe = (const float*)d_in[3];
    const float* tab = (const float*)d_in[4];
    const float* trans = (const float*)d_in[5];
    const float* l1_Wih_f = (const float*)d_in[6];
    const float* l1_Whh_f = (const float*)d_in[7];
    const float* l1_b_f = (const float*)d_in[8];
    const float* l1_Wih_r = (const float*)d_in[9];
    const float* l1_Whh_r = (const float*)d_in[10];
    const float* l1_b_r = (const float*)d_in[11];
    const float* l2_Wih_f = (const float*)d_in[12];
    const float* l2_Whh_f = (const float*)d_in[13];
    const float* l2_b_f = (const float*)d_in[14];
    const float* l2_Wih_r = (const float*)d_in[15];
    const float* l2_Whh_r = (const float*)d_in[16];
    const float* l2_b_r = (const float*)d_in[17];
    const float* gtW = (const float*)d_in[18];
    const float* gtb = (const float*)d_in[19];
    const float* c1W = (const float*)d_in[20];
    const float* c1b = (const float*)d_in[21];
    const float* c2W = (const float*)d_in[22];
    const float* c2b = (const float*)d_in[23];
    const float* c3W = (const float*)d_in[24];
    const float* c3b = (const float*)d_in[25];
    const float* h01 = (const float*)d_in[26];
    const float* c01 = (const float*)d_in[27];
    const float* h02 = (const float*)d_in[28];
    const float* c02 = (const float*)d_in[29];

    u16* emb = (u16*)d_ws;                 // 16384*320
    u16* wih1f = emb + 5242880;            // 1024*320
    u16* wih1r = wih1f + 327680;
    u16* wih2f = wih1r + 327680;           // 1024*512
    u16* wih2r = wih2f + 524288;
    u8* w81f = (u8*)(wih2r + 524288);      // 1024*256 fp8 each
    u8* w81r = w81f + 262144;
    u8* w82f = w81r + 262144;
    u8* w82r = w82f + 262144;
    u16* xgf = (u16*)(w82r + 262144);      // 16384*1024
    u16* xgr = xgf + 16777216;
    u16* o1 = xgr + 16777216;              // 16384*512
    u16* o2 = o1 + 8388608;
    float* gt = (float*)(o2 + 8388608);    // 16384
    float* hs2 = gt + 16384;               // 16384*512

    float* out_pred = (float*)d_out;
    float* out_loss = out_pred + B * T;

    hipMemsetAsync(out_loss, 0, sizeof(float), stream);

    // casts
    k_cast_emb<<<2560, 256, 0, stream>>>(ids, tab, emb);
    k_cast_pad<<<160, 256, 0, stream>>>(l1_Wih_f, wih1f, 1024, 300, 320);
    k_cast_pad<<<160, 256, 0, stream>>>(l1_Wih_r, wih1r, 1024, 300, 320);
    k_cast_pad<<<256, 256, 0, stream>>>(l2_Wih_f, wih2f, 1024, 512, 512);
    k_cast_pad<<<256, 256, 0, stream>>>(l2_Wih_r, wih2r, 1024, 512, 512);
    k_cast_w8<<<256, 256, 0, stream>>>(l1_Whh_f, w81f);
    k_cast_w8<<<256, 256, 0, stream>>>(l1_Whh_r, w81r);
    k_cast_w8<<<256, 256, 0, stream>>>(l2_Whh_f, w82f);
    k_cast_w8<<<256, 256, 0, stream>>>(l2_Whh_r, w82r);

    dim3 ggrid(HD4 / 128, (B * T) / 128);

    // layer 1
    k_gemm_mfma<<<ggrid, 256, 0, stream>>>(emb, wih1f, l1_b_f, xgf, 320);
    k_gemm_mfma<<<ggrid, 256, 0, stream>>>(emb, wih1r, l1_b_r, xgr, 320);
    k_recur<<<16, 512, 0, stream>>>(xgf, xgr, w81f, w81r, h01, c01, o1);

    // layer 2
    k_gemm_mfma<<<ggrid, 256, 0, stream>>>(o1, wih2f, l2_b_f, xgf, 512);
    k_gemm_mfma<<<ggrid, 256, 0, stream>>>(o1, wih2r, l2_b_r, xgr, 512);
    k_recur<<<16, 512, 0, stream>>>(xgf, xgr, w82f, w82r, h02, c02, o2);

    // heads
    k_gt<<<(B * T) / 4, 256, 0, stream>>>(o1, gtW, gtb, gt);
    k_scan<<<2 * B, 256, 0, stream>>>(o2, gt, hs2);
    k_cls<<<(B * T) / 4, 256, 0, stream>>>(o1, hs2, c1W, c1b, c2W, c2b, c3W, c3b, trans,
                                           y_op, y_bd, y_oe, out_pred, out_loss);
}

// Round 15
// 1105.051 us; speedup vs baseline: 1.5102x; 1.5102x over previous
//
#include <hip/hip_runtime.h>
#include <math.h>

#define B 128
#define T 128
#define H 256
#define E 300
#define HD4 1024
#define D2H 512

typedef unsigned short u16;
typedef unsigned long long u64;
typedef __attribute__((ext_vector_type(8))) short bf16x8;
typedef __attribute__((ext_vector_type(4))) float f32x4;
typedef __attribute__((address_space(1))) void as1_void;
typedef __attribute__((address_space(3))) void as3_void;

__device__ __forceinline__ float sigm(float x) { return 1.0f / (1.0f + expf(-x)); }
__device__ __forceinline__ float fast_sigm(float x) { return 1.0f / (1.0f + __expf(-x)); }
__device__ __forceinline__ float fast_tanh(float x) {
    return 1.0f - 2.0f / (__expf(2.0f * x) + 1.0f);
}
__device__ __forceinline__ float b2f(u16 u) { return __uint_as_float(((unsigned)u) << 16); }
__device__ __forceinline__ u16 f2b(float f) {
    unsigned u = __float_as_uint(f);
    unsigned r = u + 0x7FFFu + ((u >> 16) & 1u);
    return (u16)(r >> 16);
}
__device__ __forceinline__ int tag4(u64 v) {
    return (int)((v & 1) | ((v >> 15) & 2) | ((v >> 30) & 4) | ((v >> 45) & 8));
}

// ---------- embedding gather + cast + pad to K=320 ----------
__global__ __launch_bounds__(256) void k_cast_emb(const int* __restrict__ ids,
                                                  const float* __restrict__ tab,
                                                  u16* __restrict__ dst) {
    int idx = blockIdx.x * 256 + threadIdx.x;
    int row = idx / 40, kc = (idx - row * 40) * 8;
    if (row >= B * T) return;
    int id = ids[row];
    const float* src = tab + (size_t)id * E + kc;
    bf16x8 v;
#pragma unroll
    for (int j = 0; j < 8; ++j) {
        float fv = 0.0f;
        if (kc + j < E) fv = src[j];
        v[j] = (short)f2b(fv);
    }
    *(bf16x8*)(dst + (size_t)row * 320 + kc) = v;
}

// ---------- generic fp32 [N][Kin] -> bf16 [N][Kpad] ----------
__global__ __launch_bounds__(256) void k_cast_pad(const float* __restrict__ src,
                                                  u16* __restrict__ dst,
                                                  int N, int Kin, int Kpad) {
    int idx = blockIdx.x * 256 + threadIdx.x;
    int rk = Kpad >> 3;
    int row = idx / rk, kc = (idx - row * rk) * 8;
    if (row >= N) return;
    const float* s = src + (size_t)row * Kin + kc;
    bf16x8 v;
#pragma unroll
    for (int j = 0; j < 8; ++j) {
        float fv = 0.0f;
        if (kc + j < Kin) fv = s[j];
        v[j] = (short)f2b(fv);
    }
    *(bf16x8*)(dst + (size_t)row * Kpad + kc) = v;
}

// ---------- 4 Whh matrices f32 [1024][256] -> bf16, one launch ----------
__global__ __launch_bounds__(256) void k_cast_whh4(
    const float* __restrict__ s0, const float* __restrict__ s1,
    const float* __restrict__ s2, const float* __restrict__ s3,
    u16* __restrict__ d0, u16* __restrict__ d1,
    u16* __restrict__ d2, u16* __restrict__ d3) {
    int m = blockIdx.x >> 7;
    int idx = (blockIdx.x & 127) * 256 + threadIdx.x;   // over 32768 per matrix
    const float* s = (m == 0) ? s0 : (m == 1) ? s1 : (m == 2) ? s2 : s3;
    u16* d = (m == 0) ? d0 : (m == 1) ? d1 : (m == 2) ? d2 : d3;
    const float* sp = s + (size_t)idx * 8;
    bf16x8 v;
#pragma unroll
    for (int j = 0; j < 8; ++j) v[j] = (short)f2b(sp[j]);
    *(bf16x8*)(d + (size_t)idx * 8) = v;
}

// ---------- MFMA GEMM, both dirs in one launch (grid.x = 16 over N=2048) ----
// out[(t*B+b)][n] = bf16( A[m]·W[n] + bias[n] ), n gate-major per dir.
__global__ __launch_bounds__(256) void k_gemm_mfma(
    const u16* __restrict__ A,
    const u16* __restrict__ Wf, const u16* __restrict__ Wr,
    const float* __restrict__ bias_f, const float* __restrict__ bias_r,
    u16* __restrict__ outf, u16* __restrict__ outr, int Kpad) {
    __shared__ u16 aL[128 * 32];
    __shared__ u16 bL[128 * 32];
    int n0g = blockIdx.x * 128;
    const u16* W = (n0g < 1024) ? Wf : Wr;
    const float* bias = (n0g < 1024) ? bias_f : bias_r;
    u16* out = (n0g < 1024) ? outf : outr;
    const int n0 = n0g & 1023;
    const int m0 = blockIdx.y * 128;
    const int tid = threadIdx.x, wid = tid >> 6, l = tid & 63;
    const int wm = wid >> 1, wn = wid & 1;
    const int srow = wid * 16 + (l >> 2);
    const int scol = (l & 3) * 8;

    f32x4 acc[4][4] = {};

    for (int k0 = 0; k0 < Kpad; k0 += 32) {
#pragma unroll
        for (int c = 0; c < 2; ++c) {
            const u16* ga = A + (size_t)(m0 + c * 64 + srow) * Kpad + k0 + scol;
            const u16* gb = W + (size_t)(n0 + c * 64 + srow) * Kpad + k0 + scol;
            __builtin_amdgcn_global_load_lds((const as1_void*)ga,
                                             (as3_void*)&aL[(c * 64 + wid * 16) * 32],
                                             16, 0, 0);
            __builtin_amdgcn_global_load_lds((const as1_void*)gb,
                                             (as3_void*)&bL[(c * 64 + wid * 16) * 32],
                                             16, 0, 0);
        }
        __syncthreads();
        bf16x8 af[4], bf[4];
#pragma unroll
        for (int i = 0; i < 4; ++i)
            af[i] = *(const bf16x8*)&aL[(wm * 64 + i * 16 + (l & 15)) * 32 + (l >> 4) * 8];
#pragma unroll
        for (int j = 0; j < 4; ++j)
            bf[j] = *(const bf16x8*)&bL[(wn * 64 + j * 16 + (l & 15)) * 32 + (l >> 4) * 8];
#pragma unroll
        for (int i = 0; i < 4; ++i)
#pragma unroll
            for (int j = 0; j < 4; ++j)
                acc[i][j] = __builtin_amdgcn_mfma_f32_16x16x32_bf16(af[i], bf[j], acc[i][j], 0, 0, 0);
        __syncthreads();
    }

    float bv[4];
#pragma unroll
    for (int j = 0; j < 4; ++j) bv[j] = bias[n0 + wn * 64 + j * 16 + (l & 15)];
#pragma unroll
    for (int i = 0; i < 4; ++i) {
        int mbase = m0 + wm * 64 + i * 16 + (l >> 4) * 4;
#pragma unroll
        for (int r = 0; r < 4; ++r) {
            int m = mbase + r;
            int bb = m >> 7, tt = m & 127;   // m = b*T + t
            u16* orow = out + (size_t)(tt * B + bb) * HD4 + n0 + wn * 64 + (l & 15);
#pragma unroll
            for (int j = 0; j < 4; ++j) orow[j * 16] = f2b(acc[i][j][r] + bv[j]);
        }
    }
}

// ---------- persistent bi-LSTM recurrence (R9, proven 380us/layer) ----------
// grid 64 = us(4) x [d(2) x bc(8)], 256 threads. Weights (64u x 4g x K256 = 128KB)
// LDS-resident, gate-major tiles: lane owns 4 CONSECUTIVE u -> its h output is one
// u64. h exchange: relaxed agent u64 stores carrying a 4-bit step tag in the bf16
// LSBs; consumers poll their own words until tag == s&15. No fences, no flags.
__global__ __launch_bounds__(256) void k_recur(
    const u16* __restrict__ xg_f, const u16* __restrict__ xg_r,
    const u16* __restrict__ Whf, const u16* __restrict__ Whr,
    const float* __restrict__ h0, const float* __restrict__ c0,
    u16* __restrict__ hbuf, u16* __restrict__ o) {
    const int bid = blockIdx.x;
    const int us = bid >> 4;        // u-slice 0..3
    const int gidx = bid & 15;      // group = (d, bc)
    const int d = gidx >> 3;
    const int bc = gidx & 7;
    const int b0 = bc * 16;
    const u16* xg = d ? xg_r : xg_f;
    const u16* W = d ? Whr : Whf;
    const int tid = threadIdx.x, w = tid >> 6, l = tid & 63;
    const int q = l >> 4, b = l & 15;

    __shared__ u16 flds[65536];        // 128KB weights, fragment-linear
    __shared__ u16 h_lds[16][272];     // full 256-u h for 16 batches

    // ---- weights into LDS: tile (w,g,ks); lane stores exactly its 16B fragment
#pragma unroll
    for (int g = 0; g < 4; ++g)
#pragma unroll
        for (int ks = 0; ks < 8; ++ks) {
            bf16x8 v = *(const bf16x8*)&W[(size_t)(g * 256 + us * 64 + w * 16 + b) * 256 +
                                          ks * 32 + q * 8];
            *(bf16x8*)&flds[((w * 4 + g) * 8 + ks) * 512 + l * 8] = v;
        }

    // ---- c-state: lane owns cells (b, u = us*64 + w*16 + q*4 + r), r=0..3
    f32x4 creg = *(const f32x4*)&c0[(size_t)(d * B + b0 + b) * H + us * 64 + w * 16 + q * 4];

    // ---- h(0) into h_lds
    {
        int bb = tid >> 4, u0i = (tid & 15) * 16;
        const float* hp = h0 + (size_t)(d * B + b0 + bb) * H + u0i;
#pragma unroll
        for (int j = 0; j < 16; ++j) h_lds[bb][u0i + j] = f2b(hp[j]);
    }
    __syncthreads();

    for (int s = 0; s < T; ++s) {
        const int t = d ? (T - 1 - s) : s;

        // xq prefetch (4 gates x 4 consecutive u = 4 u64), independent of h
        u64 xq[4];
#pragma unroll
        for (int g = 0; g < 4; ++g)
            xq[g] = *(const u64*)&xg[((size_t)t * B + b0 + b) * HD4 + g * 256 + us * 64 +
                                     w * 16 + q * 4];

        if (s > 0) {
            const int want = s & 15;
            const size_t pbase = (size_t)(s & 1) * 2 * B * H;
#pragma unroll
            for (int ci = 0; ci < 3; ++ci) {
                int cc = ci + (ci >= us);    // the 3 remote chunks
                const u64* src = (const u64*)(hbuf + pbase +
                                              (size_t)(d * B + b0 + (tid >> 4)) * H +
                                              cc * 64 + (tid & 15) * 4);
                u64 v;
                do {
                    v = __hip_atomic_load(src, __ATOMIC_RELAXED, __HIP_MEMORY_SCOPE_AGENT);
                } while (tag4(v) != want);
                *(u64*)&h_lds[tid >> 4][cc * 64 + (tid & 15) * 4] = v;
            }
        }
        __syncthreads();

        // gates = W · h
        bf16x8 hf[8];
#pragma unroll
        for (int ks = 0; ks < 8; ++ks)
            hf[ks] = *(const bf16x8*)&h_lds[b][ks * 32 + q * 8];
        f32x4 acc[4] = {};
#pragma unroll
        for (int g = 0; g < 4; ++g)
#pragma unroll
            for (int ks = 0; ks < 8; ++ks) {
                bf16x8 wf = *(const bf16x8*)&flds[((w * 4 + g) * 8 + ks) * 512 + l * 8];
                acc[g] = __builtin_amdgcn_mfma_f32_16x16x32_bf16(wf, hf[ks], acc[g], 0, 0, 0);
            }

        // cell update: acc[g][r] = gate g of (b, u = base + r)
        u64 hvt = 0, hvc = 0;
        const int tagv = (s + 1) & 15;
#pragma unroll
        for (int r = 0; r < 4; ++r) {
            float gi = acc[0][r] + b2f((u16)(xq[0] >> (16 * r)));
            float gf = acc[1][r] + b2f((u16)(xq[1] >> (16 * r)));
            float gg = acc[2][r] + b2f((u16)(xq[2] >> (16 * r)));
            float go = acc[3][r] + b2f((u16)(xq[3] >> (16 * r)));
            float cn = fast_sigm(gf) * creg[r] + fast_sigm(gi) * fast_tanh(gg);
            float hn = fast_sigm(go) * fast_tanh(cn);
            creg[r] = cn;
            u16 hb = f2b(hn);
            hvc |= (u64)hb << (16 * r);
            hvt |= (u64)((hb & 0xFFFEu) | (u16)((tagv >> r) & 1)) << (16 * r);
        }
        __syncthreads();   // all h_lds reads done before overwrite

        // own chunk straight to LDS; remote consumers get the tagged copy
        *(u64*)&h_lds[b][us * 64 + w * 16 + q * 4] = hvc;
        if (s < T - 1) {
            u64* hdst = (u64*)(hbuf + (size_t)((s + 1) & 1) * 2 * B * H +
                               (size_t)(d * B + b0 + b) * H + us * 64 + w * 16 + q * 4);
            __hip_atomic_store(hdst, hvt, __ATOMIC_RELAXED, __HIP_MEMORY_SCOPE_AGENT);
        }
        *(u64*)&o[((size_t)(b0 + b) * T + t) * D2H + d * H + us * 64 + w * 16 + q * 4] = hvc;
    }
}

// ---------- gt = sigmoid(o1 · gt_W + gt_b) ----------
__global__ __launch_bounds__(256) void k_gt(const u16* __restrict__ o1,
                                            const float* __restrict__ gtW,
                                            const float* __restrict__ gtb,
                                            float* __restrict__ gt) {
    int row = blockIdx.x * 4 + (threadIdx.x >> 6);
    int lane = threadIdx.x & 63;
    const u16* x = o1 + (size_t)row * D2H;
    float p = 0.f;
    for (int j = lane; j < D2H; j += 64) p += b2f(x[j]) * gtW[j];
#pragma unroll
    for (int off = 32; off; off >>= 1) p += __shfl_down(p, off);
    if (lane == 0) gt[row] = sigm(p + gtb[0]);
}

// ---------- gated temporal scan ----------
__global__ void k_scan(const u16* __restrict__ o2, const float* __restrict__ gt,
                       float* __restrict__ hs2) {
    int b = blockIdx.x >> 1;
    int f = ((blockIdx.x & 1) << 8) + threadIdx.x;
    const u16* src = o2 + (size_t)b * T * D2H + f;
    float* dst = hs2 + (size_t)b * T * D2H + f;
    float prev = b2f(src[0]);
    dst[0] = prev;
    for (int t = 1; t < T; ++t) {
        float g = gt[b * T + t];
        prev = g * b2f(src[(size_t)t * D2H]) + (1.0f - g) * prev;
        dst[(size_t)t * D2H] = prev;
    }
}

// ---------- classifiers + softmax + NLL + argmax ----------
__global__ __launch_bounds__(256) void k_cls(
    const u16* __restrict__ o1, const float* __restrict__ hs2,
    const float* __restrict__ c1W, const float* __restrict__ c1b,
    const float* __restrict__ c2W, const float* __restrict__ c2b,
    const float* __restrict__ c3W, const float* __restrict__ c3b,
    const float* __restrict__ trans, const float* __restrict__ y_op,
    const float* __restrict__ y_bd, const float* __restrict__ y_oe,
    float* __restrict__ out_pred, float* __restrict__ out_loss) {
    int row = blockIdx.x * 4 + (threadIdx.x >> 6);
    int lane = threadIdx.x & 63;
    const u16* x1 = o1 + (size_t)row * D2H;
    const float* x2 = hs2 + (size_t)row * D2H;
    float p1[5] = {}, p2[13] = {}, p3[2] = {};
    for (int j = lane; j < D2H; j += 64) {
        float a = b2f(x1[j]), h = x2[j];
#pragma unroll
        for (int c = 0; c < 5; ++c) p1[c] += a * c1W[c * D2H + j];
#pragma unroll
        for (int c = 0; c < 13; ++c) p2[c] += h * c2W[c * D2H + j];
#pragma unroll
        for (int c = 0; c < 2; ++c) p3[c] += a * c3W[c * D2H + j];
    }
#pragma unroll
    for (int c = 0; c < 5; ++c)
#pragma unroll
        for (int off = 32; off; off >>= 1) p1[c] += __shfl_down(p1[c], off);
#pragma unroll
    for (int c = 0; c < 13; ++c)
#pragma unroll
        for (int off = 32; off; off >>= 1) p2[c] += __shfl_down(p2[c], off);
#pragma unroll
    for (int c = 0; c < 2; ++c)
#pragma unroll
        for (int off = 32; off; off >>= 1) p3[c] += __shfl_down(p3[c], off);

    if (lane == 0) {
        float z1[5], z2[13], z3[2];
        float m = -1e30f, s;
        for (int c = 0; c < 5; ++c) { z1[c] = p1[c] + c1b[c]; m = fmaxf(m, z1[c]); }
        s = 0.f;
        for (int c = 0; c < 5; ++c) { z1[c] = expf(z1[c] - m); s += z1[c]; }
        for (int c = 0; c < 5; ++c) z1[c] /= s;
        m = -1e30f;
        for (int c = 0; c < 13; ++c) { z2[c] = p2[c] + c2b[c]; m = fmaxf(m, z2[c]); }
        s = 0.f;
        for (int c = 0; c < 13; ++c) { z2[c] = expf(z2[c] - m); s += z2[c]; }
        for (int c = 0; c < 13; ++c) z2[c] /= s;
        m = fmaxf(p3[0] + c3b[0], p3[1] + c3b[1]);
        z3[0] = expf(p3[0] + c3b[0] - m);
        z3[1] = expf(p3[1] + c3b[1] - m);
        s = z3[0] + z3[1];
        z3[0] /= s; z3[1] /= s;

        float at = 0.f;
        for (int c = 0; c < 5; ++c) at += z1[c] * z1[c];
        at *= 0.5f;

        float lsum = 0.f, best = -1e30f;
        int arg = 0;
        for (int c = 0; c < 13; ++c) {
            float s2v = 0.f;
            for (int j = 0; j < 5; ++j) s2v += z1[j] * trans[j * 13 + c];
            float v = at * s2v + (1.0f - at) * z2[c];
            lsum += y_op[(size_t)row * 13 + c] * logf(v);
            if (v > best) { best = v; arg = c; }
        }
        for (int j = 0; j < 5; ++j) lsum += y_bd[(size_t)row * 5 + j] * logf(z1[j]);
        for (int k = 0; k < 2; ++k) lsum += y_oe[(size_t)row * 2 + k] * logf(z3[k]);
        atomicAdd(out_loss, -lsum * (1.0f / T));
        out_pred[row] = (float)arg;
    }
}

extern "C" void kernel_launch(void* const* d_in, const int* in_sizes, int n_in,
                              void* d_out, int out_size, void* d_ws, size_t ws_size,
                              hipStream_t stream) {
    const int* ids = (const int*)d_in[0];
    const float* y_op = (const float*)d_in[1];
    const float* y_bd = (const float*)d_in[2];
    const float* y_oe = (const float*)d_in[3];
    const float* tab = (const float*)d_in[4];
    const float* trans = (const float*)d_in[5];
    const float* l1_Wih_f = (const float*)d_in[6];
    const float* l1_Whh_f = (const float*)d_in[7];
    const float* l1_b_f = (const float*)d_in[8];
    const float* l1_Wih_r = (const float*)d_in[9];
    const float* l1_Whh_r = (const float*)d_in[10];
    const float* l1_b_r = (const float*)d_in[11];
    const float* l2_Wih_f = (const float*)d_in[12];
    const float* l2_Whh_f = (const float*)d_in[13];
    const float* l2_b_f = (const float*)d_in[14];
    const float* l2_Wih_r = (const float*)d_in[15];
    const float* l2_Whh_r = (const float*)d_in[16];
    const float* l2_b_r = (const float*)d_in[17];
    const float* gtW = (const float*)d_in[18];
    const float* gtb = (const float*)d_in[19];
    const float* c1W = (const float*)d_in[20];
    const float* c1b = (const float*)d_in[21];
    const float* c2W = (const float*)d_in[22];
    const float* c2b = (const float*)d_in[23];
    const float* c3W = (const float*)d_in[24];
    const float* c3b = (const float*)d_in[25];
    const float* h01 = (const float*)d_in[26];
    const float* c01 = (const float*)d_in[27];
    const float* h02 = (const float*)d_in[28];
    const float* c02 = (const float*)d_in[29];

    u16* emb = (u16*)d_ws;                 // 16384*320
    u16* wih1f = emb + 5242880;            // 1024*320
    u16* wih1r = wih1f + 327680;
    u16* wih2f = wih1r + 327680;           // 1024*512
    u16* wih2r = wih2f + 524288;
    u16* whh1f = wih2r + 524288;           // 1024*256
    u16* whh1r = whh1f + 262144;
    u16* whh2f = whh1r + 262144;
    u16* whh2r = whh2f + 262144;
    u16* xgf = whh2r + 262144;             // 16384*1024
    u16* xgr = xgf + 16777216;
    u16* o1 = xgr + 16777216;              // 16384*512
    u16* o2 = o1 + 8388608;
    u16* hbuf = o2 + 8388608;              // 2 layers * 2 parities * 2*B*H
    float* gt = (float*)(hbuf + 262144);   // 16384
    float* hs2 = gt + 16384;               // 16384*512

    float* out_pred = (float*)d_out;
    float* out_loss = out_pred + B * T;

    hipMemsetAsync(out_loss, 0, sizeof(float), stream);
    hipMemsetAsync(hbuf, 0, 262144 * sizeof(u16), stream);

    // casts
    k_cast_emb<<<2560, 256, 0, stream>>>(ids, tab, emb);
    k_cast_pad<<<160, 256, 0, stream>>>(l1_Wih_f, wih1f, 1024, 300, 320);
    k_cast_pad<<<160, 256, 0, stream>>>(l1_Wih_r, wih1r, 1024, 300, 320);
    k_cast_pad<<<256, 256, 0, stream>>>(l2_Wih_f, wih2f, 1024, 512, 512);
    k_cast_pad<<<256, 256, 0, stream>>>(l2_Wih_r, wih2r, 1024, 512, 512);
    k_cast_whh4<<<512, 256, 0, stream>>>(l1_Whh_f, l1_Whh_r, l2_Whh_f, l2_Whh_r,
                                         whh1f, whh1r, whh2f, whh2r);

    dim3 ggrid(2048 / 128, (B * T) / 128);

    // layer 1 (both dirs, one launch)
    k_gemm_mfma<<<ggrid, 256, 0, stream>>>(emb, wih1f, wih1r, l1_b_f, l1_b_r,
                                           xgf, xgr, 320);
    k_recur<<<64, 256, 0, stream>>>(xgf, xgr, whh1f, whh1r, h01, c01, hbuf, o1);

    // layer 2 (both dirs, one launch)
    k_gemm_mfma<<<ggrid, 256, 0, stream>>>(o1, wih2f, wih2r, l2_b_f, l2_b_r,
                                           xgf, xgr, 512);
    k_recur<<<64, 256, 0, stream>>>(xgf, xgr, whh2f, whh2r, h02, c02, hbuf + 131072, o2);

    // heads
    k_gt<<<(B * T) / 4, 256, 0, stream>>>(o1, gtW, gtb, gt);
    k_scan<<<2 * B, 256, 0, stream>>>(o2, gt, hs2);
    k_cls<<<(B * T) / 4, 256, 0, stream>>>(o1, hs2, c1W, c1b, c2W, c2b, c3W, c3b, trans,
                                           y_op, y_bd, y_oe, out_pred, out_loss);
}

// Round 16
// 1084.186 us; speedup vs baseline: 1.5393x; 1.0192x over previous
//
#include <hip/hip_runtime.h>
#include <math.h>

#define B 128
#define T 128
#define H 256
#define E 300
#define HD4 1024
#define D2H 512

typedef unsigned short u16;
typedef unsigned long long u64;
typedef __attribute__((ext_vector_type(8))) short bf16x8;
typedef __attribute__((ext_vector_type(4))) float f32x4;
typedef __attribute__((address_space(1))) void as1_void;
typedef __attribute__((address_space(3))) void as3_void;

__device__ __forceinline__ float sigm(float x) { return 1.0f / (1.0f + expf(-x)); }
__device__ __forceinline__ float fast_sigm(float x) { return 1.0f / (1.0f + __expf(-x)); }
__device__ __forceinline__ float fast_tanh(float x) {
    return 1.0f - 2.0f / (__expf(2.0f * x) + 1.0f);
}
__device__ __forceinline__ float b2f(u16 u) { return __uint_as_float(((unsigned)u) << 16); }
__device__ __forceinline__ u16 f2b(float f) {
    unsigned u = __float_as_uint(f);
    unsigned r = u + 0x7FFFu + ((u >> 16) & 1u);
    return (u16)(r >> 16);
}
__device__ __forceinline__ int tag4(u64 v) {
    return (int)((v & 1) | ((v >> 15) & 2) | ((v >> 30) & 4) | ((v >> 45) & 8));
}

// ---------- embedding gather + cast + pad to K=320 ----------
__global__ __launch_bounds__(256) void k_cast_emb(const int* __restrict__ ids,
                                                  const float* __restrict__ tab,
                                                  u16* __restrict__ dst) {
    int idx = blockIdx.x * 256 + threadIdx.x;
    int row = idx / 40, kc = (idx - row * 40) * 8;
    if (row >= B * T) return;
    int id = ids[row];
    const float* src = tab + (size_t)id * E + kc;
    bf16x8 v;
#pragma unroll
    for (int j = 0; j < 8; ++j) {
        float fv = 0.0f;
        if (kc + j < E) fv = src[j];
        v[j] = (short)f2b(fv);
    }
    *(bf16x8*)(dst + (size_t)row * 320 + kc) = v;
}

// ---------- generic fp32 [N][Kin] -> bf16 [N][Kpad] ----------
__global__ __launch_bounds__(256) void k_cast_pad(const float* __restrict__ src,
                                                  u16* __restrict__ dst,
                                                  int N, int Kin, int Kpad) {
    int idx = blockIdx.x * 256 + threadIdx.x;
    int rk = Kpad >> 3;
    int row = idx / rk, kc = (idx - row * rk) * 8;
    if (row >= N) return;
    const float* s = src + (size_t)row * Kin + kc;
    bf16x8 v;
#pragma unroll
    for (int j = 0; j < 8; ++j) {
        float fv = 0.0f;
        if (kc + j < Kin) fv = s[j];
        v[j] = (short)f2b(fv);
    }
    *(bf16x8*)(dst + (size_t)row * Kpad + kc) = v;
}

// ---------- 4 Whh matrices f32 [1024][256] -> bf16, one launch ----------
__global__ __launch_bounds__(256) void k_cast_whh4(
    const float* __restrict__ s0, const float* __restrict__ s1,
    const float* __restrict__ s2, const float* __restrict__ s3,
    u16* __restrict__ d0, u16* __restrict__ d1,
    u16* __restrict__ d2, u16* __restrict__ d3) {
    int m = blockIdx.x >> 7;
    int idx = (blockIdx.x & 127) * 256 + threadIdx.x;   // over 32768 per matrix
    const float* s = (m == 0) ? s0 : (m == 1) ? s1 : (m == 2) ? s2 : s3;
    u16* d = (m == 0) ? d0 : (m == 1) ? d1 : (m == 2) ? d2 : d3;
    const float* sp = s + (size_t)idx * 8;
    bf16x8 v;
#pragma unroll
    for (int j = 0; j < 8; ++j) v[j] = (short)f2b(sp[j]);
    *(bf16x8*)(d + (size_t)idx * 8) = v;
}

// ---------- MFMA GEMM, both dirs in one launch (grid.x = 16 over N=2048) ----
// out[(t*B+b)][n] = bf16( A[m]·W[n] + bias[n] ), n gate-major per dir.
__global__ __launch_bounds__(256) void k_gemm_mfma(
    const u16* __restrict__ A,
    const u16* __restrict__ Wf, const u16* __restrict__ Wr,
    const float* __restrict__ bias_f, const float* __restrict__ bias_r,
    u16* __restrict__ outf, u16* __restrict__ outr, int Kpad) {
    __shared__ u16 aL[128 * 32];
    __shared__ u16 bL[128 * 32];
    int n0g = blockIdx.x * 128;
    const u16* W = (n0g < 1024) ? Wf : Wr;
    const float* bias = (n0g < 1024) ? bias_f : bias_r;
    u16* out = (n0g < 1024) ? outf : outr;
    const int n0 = n0g & 1023;
    const int m0 = blockIdx.y * 128;
    const int tid = threadIdx.x, wid = tid >> 6, l = tid & 63;
    const int wm = wid >> 1, wn = wid & 1;
    const int srow = wid * 16 + (l >> 2);
    const int scol = (l & 3) * 8;

    f32x4 acc[4][4] = {};

    for (int k0 = 0; k0 < Kpad; k0 += 32) {
#pragma unroll
        for (int c = 0; c < 2; ++c) {
            const u16* ga = A + (size_t)(m0 + c * 64 + srow) * Kpad + k0 + scol;
            const u16* gb = W + (size_t)(n0 + c * 64 + srow) * Kpad + k0 + scol;
            __builtin_amdgcn_global_load_lds((const as1_void*)ga,
                                             (as3_void*)&aL[(c * 64 + wid * 16) * 32],
                                             16, 0, 0);
            __builtin_amdgcn_global_load_lds((const as1_void*)gb,
                                             (as3_void*)&bL[(c * 64 + wid * 16) * 32],
                                             16, 0, 0);
        }
        __syncthreads();
        bf16x8 af[4], bf[4];
#pragma unroll
        for (int i = 0; i < 4; ++i)
            af[i] = *(const bf16x8*)&aL[(wm * 64 + i * 16 + (l & 15)) * 32 + (l >> 4) * 8];
#pragma unroll
        for (int j = 0; j < 4; ++j)
            bf[j] = *(const bf16x8*)&bL[(wn * 64 + j * 16 + (l & 15)) * 32 + (l >> 4) * 8];
#pragma unroll
        for (int i = 0; i < 4; ++i)
#pragma unroll
            for (int j = 0; j < 4; ++j)
                acc[i][j] = __builtin_amdgcn_mfma_f32_16x16x32_bf16(af[i], bf[j], acc[i][j], 0, 0, 0);
        __syncthreads();
    }

    float bv[4];
#pragma unroll
    for (int j = 0; j < 4; ++j) bv[j] = bias[n0 + wn * 64 + j * 16 + (l & 15)];
#pragma unroll
    for (int i = 0; i < 4; ++i) {
        int mbase = m0 + wm * 64 + i * 16 + (l >> 4) * 4;
#pragma unroll
        for (int r = 0; r < 4; ++r) {
            int m = mbase + r;
            int bb = m >> 7, tt = m & 127;   // m = b*T + t
            u16* orow = out + (size_t)(tt * B + bb) * HD4 + n0 + wn * 64 + (l & 15);
#pragma unroll
            for (int j = 0; j < 4; ++j) orow[j * 16] = f2b(acc[i][j][r] + bv[j]);
        }
    }
}

// ---------- persistent bi-LSTM recurrence (R9 base + CONCURRENT 3-chunk poll) ----
// grid 64 = us(4) x [d(2) x bc(8)], 256 threads. Weights (64u x 4g x K256 = 128KB)
// LDS-resident. h exchange: relaxed agent u64 stores with 4-bit step tag in bf16
// LSBs. NEW vs R9: the 3 remote-chunk polls run CONCURRENTLY (all loads in flight
// each iteration) instead of 3 serialized do-while loops -> detect-all ~1 MALL RT.
__global__ __launch_bounds__(256) void k_recur(
    const u16* __restrict__ xg_f, const u16* __restrict__ xg_r,
    const u16* __restrict__ Whf, const u16* __restrict__ Whr,
    const float* __restrict__ h0, const float* __restrict__ c0,
    u16* __restrict__ hbuf, u16* __restrict__ o) {
    const int bid = blockIdx.x;
    const int us = bid >> 4;        // u-slice 0..3
    const int gidx = bid & 15;      // group = (d, bc)
    const int d = gidx >> 3;
    const int bc = gidx & 7;
    const int b0 = bc * 16;
    const u16* xg = d ? xg_r : xg_f;
    const u16* W = d ? Whr : Whf;
    const int tid = threadIdx.x, w = tid >> 6, l = tid & 63;
    const int q = l >> 4, b = l & 15;

    __shared__ u16 flds[65536];        // 128KB weights, fragment-linear
    __shared__ u16 h_lds[16][272];     // full 256-u h for 16 batches

    // ---- weights into LDS: tile (w,g,ks); lane stores exactly its 16B fragment
#pragma unroll
    for (int g = 0; g < 4; ++g)
#pragma unroll
        for (int ks = 0; ks < 8; ++ks) {
            bf16x8 v = *(const bf16x8*)&W[(size_t)(g * 256 + us * 64 + w * 16 + b) * 256 +
                                          ks * 32 + q * 8];
            *(bf16x8*)&flds[((w * 4 + g) * 8 + ks) * 512 + l * 8] = v;
        }

    // ---- c-state: lane owns cells (b, u = us*64 + w*16 + q*4 + r), r=0..3
    f32x4 creg = *(const f32x4*)&c0[(size_t)(d * B + b0 + b) * H + us * 64 + w * 16 + q * 4];

    // ---- h(0) into h_lds
    {
        int bb = tid >> 4, u0i = (tid & 15) * 16;
        const float* hp = h0 + (size_t)(d * B + b0 + bb) * H + u0i;
#pragma unroll
        for (int j = 0; j < 16; ++j) h_lds[bb][u0i + j] = f2b(hp[j]);
    }
    __syncthreads();

    // remote chunk ids (the 3 chunks this block doesn't own)
    const int cc0 = 0 + (0 >= us);
    const int cc1 = 1 + (1 >= us);
    const int cc2 = 2 + (2 >= us);
    const int prow = tid >> 4, pcol = (tid & 15) * 4;   // poll coords

    for (int s = 0; s < T; ++s) {
        const int t = d ? (T - 1 - s) : s;

        // xq prefetch (4 gates x 4 consecutive u = 4 u64), independent of h
        u64 xq[4];
#pragma unroll
        for (int g = 0; g < 4; ++g)
            xq[g] = *(const u64*)&xg[((size_t)t * B + b0 + b) * HD4 + g * 256 + us * 64 +
                                     w * 16 + q * 4];

        if (s > 0) {
            const int want = s & 15;
            const u64* base = (const u64*)(hbuf + (size_t)(s & 1) * 2 * B * H +
                                           (size_t)(d * B + b0 + prow) * H + pcol);
            const u64* p0 = base + cc0 * 16;   // 64 u16 = 16 u64 per chunk-row
            const u64* p1 = base + cc1 * 16;
            const u64* p2 = base + cc2 * 16;
            u64 v0, v1, v2;
            bool g0 = false, g1 = false, g2 = false;
            do {
                // independent loads issued together -> latencies overlap
                if (!g0) v0 = __hip_atomic_load(p0, __ATOMIC_RELAXED, __HIP_MEMORY_SCOPE_AGENT);
                if (!g1) v1 = __hip_atomic_load(p1, __ATOMIC_RELAXED, __HIP_MEMORY_SCOPE_AGENT);
                if (!g2) v2 = __hip_atomic_load(p2, __ATOMIC_RELAXED, __HIP_MEMORY_SCOPE_AGENT);
                if (!g0 && tag4(v0) == want) {
                    *(u64*)&h_lds[prow][cc0 * 64 + pcol] = v0;
                    g0 = true;
                }
                if (!g1 && tag4(v1) == want) {
                    *(u64*)&h_lds[prow][cc1 * 64 + pcol] = v1;
                    g1 = true;
                }
                if (!g2 && tag4(v2) == want) {
                    *(u64*)&h_lds[prow][cc2 * 64 + pcol] = v2;
                    g2 = true;
                }
            } while (!(g0 && g1 && g2));
        }
        __syncthreads();

        // gates = W · h
        bf16x8 hf[8];
#pragma unroll
        for (int ks = 0; ks < 8; ++ks)
            hf[ks] = *(const bf16x8*)&h_lds[b][ks * 32 + q * 8];
        f32x4 acc[4] = {};
#pragma unroll
        for (int g = 0; g < 4; ++g)
#pragma unroll
            for (int ks = 0; ks < 8; ++ks) {
                bf16x8 wf = *(const bf16x8*)&flds[((w * 4 + g) * 8 + ks) * 512 + l * 8];
                acc[g] = __builtin_amdgcn_mfma_f32_16x16x32_bf16(wf, hf[ks], acc[g], 0, 0, 0);
            }

        // cell update: acc[g][r] = gate g of (b, u = base + r)
        u64 hvt = 0, hvc = 0;
        const int tagv = (s + 1) & 15;
#pragma unroll
        for (int r = 0; r < 4; ++r) {
            float gi = acc[0][r] + b2f((u16)(xq[0] >> (16 * r)));
            float gf = acc[1][r] + b2f((u16)(xq[1] >> (16 * r)));
            float gg = acc[2][r] + b2f((u16)(xq[2] >> (16 * r)));
            float go = acc[3][r] + b2f((u16)(xq[3] >> (16 * r)));
            float cn = fast_sigm(gf) * creg[r] + fast_sigm(gi) * fast_tanh(gg);
            float hn = fast_sigm(go) * fast_tanh(cn);
            creg[r] = cn;
            u16 hb = f2b(hn);
            hvc |= (u64)hb << (16 * r);
            hvt |= (u64)((hb & 0xFFFEu) | (u16)((tagv >> r) & 1)) << (16 * r);
        }
        __syncthreads();   // all h_lds reads done before overwrite

        // own chunk straight to LDS; remote consumers get the tagged copy
        *(u64*)&h_lds[b][us * 64 + w * 16 + q * 4] = hvc;
        if (s < T - 1) {
            u64* hdst = (u64*)(hbuf + (size_t)((s + 1) & 1) * 2 * B * H +
                               (size_t)(d * B + b0 + b) * H + us * 64 + w * 16 + q * 4);
            __hip_atomic_store(hdst, hvt, __ATOMIC_RELAXED, __HIP_MEMORY_SCOPE_AGENT);
        }
        *(u64*)&o[((size_t)(b0 + b) * T + t) * D2H + d * H + us * 64 + w * 16 + q * 4] = hvc;
    }
}

// ---------- gt = sigmoid(o1 · gt_W + gt_b) ----------
__global__ __launch_bounds__(256) void k_gt(const u16* __restrict__ o1,
                                            const float* __restrict__ gtW,
                                            const float* __restrict__ gtb,
                                            float* __restrict__ gt) {
    int row = blockIdx.x * 4 + (threadIdx.x >> 6);
    int lane = threadIdx.x & 63;
    const u16* x = o1 + (size_t)row * D2H;
    float p = 0.f;
    for (int j = lane; j < D2H; j += 64) p += b2f(x[j]) * gtW[j];
#pragma unroll
    for (int off = 32; off; off >>= 1) p += __shfl_down(p, off);
    if (lane == 0) gt[row] = sigm(p + gtb[0]);
}

// ---------- gated temporal scan ----------
__global__ void k_scan(const u16* __restrict__ o2, const float* __restrict__ gt,
                       float* __restrict__ hs2) {
    int b = blockIdx.x >> 1;
    int f = ((blockIdx.x & 1) << 8) + threadIdx.x;
    const u16* src = o2 + (size_t)b * T * D2H + f;
    float* dst = hs2 + (size_t)b * T * D2H + f;
    float prev = b2f(src[0]);
    dst[0] = prev;
    for (int t = 1; t < T; ++t) {
        float g = gt[b * T + t];
        prev = g * b2f(src[(size_t)t * D2H]) + (1.0f - g) * prev;
        dst[(size_t)t * D2H] = prev;
    }
}

// ---------- classifiers + softmax + NLL + argmax ----------
__global__ __launch_bounds__(256) void k_cls(
    const u16* __restrict__ o1, const float* __restrict__ hs2,
    const float* __restrict__ c1W, const float* __restrict__ c1b,
    const float* __restrict__ c2W, const float* __restrict__ c2b,
    const float* __restrict__ c3W, const float* __restrict__ c3b,
    const float* __restrict__ trans, const float* __restrict__ y_op,
    const float* __restrict__ y_bd, const float* __restrict__ y_oe,
    float* __restrict__ out_pred, float* __restrict__ out_loss) {
    int row = blockIdx.x * 4 + (threadIdx.x >> 6);
    int lane = threadIdx.x & 63;
    const u16* x1 = o1 + (size_t)row * D2H;
    const float* x2 = hs2 + (size_t)row * D2H;
    float p1[5] = {}, p2[13] = {}, p3[2] = {};
    for (int j = lane; j < D2H; j += 64) {
        float a = b2f(x1[j]), h = x2[j];
#pragma unroll
        for (int c = 0; c < 5; ++c) p1[c] += a * c1W[c * D2H + j];
#pragma unroll
        for (int c = 0; c < 13; ++c) p2[c] += h * c2W[c * D2H + j];
#pragma unroll
        for (int c = 0; c < 2; ++c) p3[c] += a * c3W[c * D2H + j];
    }
#pragma unroll
    for (int c = 0; c < 5; ++c)
#pragma unroll
        for (int off = 32; off; off >>= 1) p1[c] += __shfl_down(p1[c], off);
#pragma unroll
    for (int c = 0; c < 13; ++c)
#pragma unroll
        for (int off = 32; off; off >>= 1) p2[c] += __shfl_down(p2[c], off);
#pragma unroll
    for (int c = 0; c < 2; ++c)
#pragma unroll
        for (int off = 32; off; off >>= 1) p3[c] += __shfl_down(p3[c], off);

    if (lane == 0) {
        float z1[5], z2[13], z3[2];
        float m = -1e30f, s;
        for (int c = 0; c < 5; ++c) { z1[c] = p1[c] + c1b[c]; m = fmaxf(m, z1[c]); }
        s = 0.f;
        for (int c = 0; c < 5; ++c) { z1[c] = expf(z1[c] - m); s += z1[c]; }
        for (int c = 0; c < 5; ++c) z1[c] /= s;
        m = -1e30f;
        for (int c = 0; c < 13; ++c) { z2[c] = p2[c] + c2b[c]; m = fmaxf(m, z2[c]); }
        s = 0.f;
        for (int c = 0; c < 13; ++c) { z2[c] = expf(z2[c] - m); s += z2[c]; }
        for (int c = 0; c < 13; ++c) z2[c] /= s;
        m = fmaxf(p3[0] + c3b[0], p3[1] + c3b[1]);
        z3[0] = expf(p3[0] + c3b[0] - m);
        z3[1] = expf(p3[1] + c3b[1] - m);
        s = z3[0] + z3[1];
        z3[0] /= s; z3[1] /= s;

        float at = 0.f;
        for (int c = 0; c < 5; ++c) at += z1[c] * z1[c];
        at *= 0.5f;

        float lsum = 0.f, best = -1e30f;
        int arg = 0;
        for (int c = 0; c < 13; ++c) {
            float s2v = 0.f;
            for (int j = 0; j < 5; ++j) s2v += z1[j] * trans[j * 13 + c];
            float v = at * s2v + (1.0f - at) * z2[c];
            lsum += y_op[(size_t)row * 13 + c] * logf(v);
            if (v > best) { best = v; arg = c; }
        }
        for (int j = 0; j < 5; ++j) lsum += y_bd[(size_t)row * 5 + j] * logf(z1[j]);
        for (int k = 0; k < 2; ++k) lsum += y_oe[(size_t)row * 2 + k] * logf(z3[k]);
        atomicAdd(out_loss, -lsum * (1.0f / T));
        out_pred[row] = (float)arg;
    }
}

extern "C" void kernel_launch(void* const* d_in, const int* in_sizes, int n_in,
                              void* d_out, int out_size, void* d_ws, size_t ws_size,
                              hipStream_t stream) {
    const int* ids = (const int*)d_in[0];
    const float* y_op = (const float*)d_in[1];
    const float* y_bd = (const float*)d_in[2];
    const float* y_oe = (const float*)d_in[3];
    const float* tab = (const float*)d_in[4];
    const float* trans = (const float*)d_in[5];
    const float* l1_Wih_f = (const float*)d_in[6];
    const float* l1_Whh_f = (const float*)d_in[7];
    const float* l1_b_f = (const float*)d_in[8];
    const float* l1_Wih_r = (const float*)d_in[9];
    const float* l1_Whh_r = (const float*)d_in[10];
    const float* l1_b_r = (const float*)d_in[11];
    const float* l2_Wih_f = (const float*)d_in[12];
    const float* l2_Whh_f = (const float*)d_in[13];
    const float* l2_b_f = (const float*)d_in[14];
    const float* l2_Wih_r = (const float*)d_in[15];
    const float* l2_Whh_r = (const float*)d_in[16];
    const float* l2_b_r = (const float*)d_in[17];
    const float* gtW = (const float*)d_in[18];
    const float* gtb = (const float*)d_in[19];
    const float* c1W = (const float*)d_in[20];
    const float* c1b = (const float*)d_in[21];
    const float* c2W = (const float*)d_in[22];
    const float* c2b = (const float*)d_in[23];
    const float* c3W = (const float*)d_in[24];
    const float* c3b = (const float*)d_in[25];
    const float* h01 = (const float*)d_in[26];
    const float* c01 = (const float*)d_in[27];
    const float* h02 = (const float*)d_in[28];
    const float* c02 = (const float*)d_in[29];

    u16* emb = (u16*)d_ws;                 // 16384*320
    u16* wih1f = emb + 5242880;            // 1024*320
    u16* wih1r = wih1f + 327680;
    u16* wih2f = wih1r + 327680;           // 1024*512
    u16* wih2r = wih2f + 524288;
    u16* whh1f = wih2r + 524288;           // 1024*256
    u16* whh1r = whh1f + 262144;
    u16* whh2f = whh1r + 262144;
    u16* whh2r = whh2f + 262144;
    u16* xgf = whh2r + 262144;             // 16384*1024
    u16* xgr = xgf + 16777216;
    u16* o1 = xgr + 16777216;              // 16384*512
    u16* o2 = o1 + 8388608;
    u16* hbuf = o2 + 8388608;              // 2 layers * 2 parities * 2*B*H
    float* gt = (float*)(hbuf + 262144);   // 16384
    float* hs2 = gt + 16384;               // 16384*512

    float* out_pred = (float*)d_out;
    float* out_loss = out_pred + B * T;

    hipMemsetAsync(out_loss, 0, sizeof(float), stream);
    hipMemsetAsync(hbuf, 0, 262144 * sizeof(u16), stream);

    // casts
    k_cast_emb<<<2560, 256, 0, stream>>>(ids, tab, emb);
    k_cast_pad<<<160, 256, 0, stream>>>(l1_Wih_f, wih1f, 1024, 300, 320);
    k_cast_pad<<<160, 256, 0, stream>>>(l1_Wih_r, wih1r, 1024, 300, 320);
    k_cast_pad<<<256, 256, 0, stream>>>(l2_Wih_f, wih2f, 1024, 512, 512);
    k_cast_pad<<<256, 256, 0, stream>>>(l2_Wih_r, wih2r, 1024, 512, 512);
    k_cast_whh4<<<512, 256, 0, stream>>>(l1_Whh_f, l1_Whh_r, l2_Whh_f, l2_Whh_r,
                                         whh1f, whh1r, whh2f, whh2r);

    dim3 ggrid(2048 / 128, (B * T) / 128);

    // layer 1 (both dirs, one launch)
    k_gemm_mfma<<<ggrid, 256, 0, stream>>>(emb, wih1f, wih1r, l1_b_f, l1_b_r,
                                           xgf, xgr, 320);
    k_recur<<<64, 256, 0, stream>>>(xgf, xgr, whh1f, whh1r, h01, c01, hbuf, o1);

    // layer 2 (both dirs, one launch)
    k_gemm_mfma<<<ggrid, 256, 0, stream>>>(o1, wih2f, wih2r, l2_b_f, l2_b_r,
                                           xgf, xgr, 512);
    k_recur<<<64, 256, 0, stream>>>(xgf, xgr, whh2f, whh2r, h02, c02, hbuf + 131072, o2);

    // heads
    k_gt<<<(B * T) / 4, 256, 0, stream>>>(o1, gtW, gtb, gt);
    k_scan<<<2 * B, 256, 0, stream>>>(o2, gt, hs2);
    k_cls<<<(B * T) / 4, 256, 0, stream>>>(o1, hs2, c1W, c1b, c2W, c2b, c3W, c3b, trans,
                                           y_op, y_bd, y_oe, out_pred, out_loss);
}